// Round 4
// baseline (186.339 us; speedup 1.0000x reference)
//
#include <hip/hip_runtime.h>
#include <hip/hip_bf16.h>

// MultiHeadAttention fused pipeline. FP32 in/out, bf16 MFMA compute, fp32 accum.
// B=2 T=2048 C=1024 H=16 D=64.
// Stage 0: convert x,W* -> bf16 fragment-major (wave frag load = 1KB burst).
// Stage 1: QKV GEMM zero-LDS streaming (round-0 proven form); RoPE + exp2
//          scale fused. Q row-major; K QK-B-frag-major; V PV-B-frag-major
//          natural k-order (8B short4v stores).
// Stage 2: attention, ZERO-LDS-K/V streaming + T15 DOUBLE-PIPELINE:
//          iteration c computes QK(c)->exp2->P(c) while running PV(c-1)
//          from the P written last iteration (LDS round-trip latency off
//          the critical path; MFMA overlaps VALU). Single per-wave P
//          buffer (same-wave DS in-order; read(c-1) precedes write(c)).
//          K/V read directly from global (L2-resident), K prefetched one
//          chunk ahead, V one chunk ahead (consumed next iteration).
// Stage 3: out GEMM zero-LDS streaming -> fp32 d_out (round-0 form).
//
// MFMA layouts (HW-verified): A[m=lane&15][k=quad*8+j]; B[n=lane&15][k=quad*8+j];
// C/D: row=quad*4+reg, col=lane&15.

typedef __hip_bfloat16 bf16;
typedef __attribute__((ext_vector_type(8))) short bf16x8;
typedef __attribute__((ext_vector_type(4))) float f32x4;
typedef __attribute__((ext_vector_type(4))) short short4v;

#define MFMA16(a, b, c) __builtin_amdgcn_mfma_f32_16x16x32_bf16((a), (b), (c), 0, 0, 0)

constexpr int Bn = 2, Hn = 16, Tn = 2048, Dn = 64, Cn = 1024;
constexpr size_t NE = (size_t)Bn * Tn * Cn;   // 4,194,304
constexpr size_t WE = (size_t)Cn * Cn;        // 1,048,576
constexpr float QSCALE = 0.125f * 1.44269504088896f;   // 1/8 * log2(e)
constexpr int PS = 68;   // P-buffer row stride in shorts (2-way banks = free)

__device__ inline unsigned short bfbits(float x) {
    bf16 b = __float2bfloat16(x);
    return *(unsigned short*)&b;
}

__device__ inline bf16x8 pack8(f32x4 a, f32x4 b) {
    bf16x8 r;
#pragma unroll
    for (int i = 0; i < 4; ++i) r[i] = (short)bfbits(a[i]);
#pragma unroll
    for (int i = 0; i < 4; ++i) r[4 + i] = (short)bfbits(b[i]);
    return r;
}

// ---------------------------------------------------------------- convert
// blocks [0,2048): x -> fragment-major. [2048,4096): W* -> fragment-major.
__global__ __launch_bounds__(256) void convert_kernel(
    const float* __restrict__ x, const float* __restrict__ wq,
    const float* __restrict__ wk, const float* __restrict__ wv,
    const float* __restrict__ wo, bf16* __restrict__ dst)
{
    int blk = blockIdx.x;
    int lane = threadIdx.x & 63;
    int lx = lane & 15, quad = lane >> 4;
    const float* src;
    size_t doff;
    if (blk < 2048) {
        int frag = blk * 4 + (threadIdx.x >> 6);   // 0..8191
        int mt = frag >> 5, kc = frag & 31;
        src = x + (size_t)(mt * 16 + lx) * Cn + kc * 32 + quad * 8;
        doff = (size_t)frag * 512 + lane * 8;
    } else {
        int w = (blk - 2048) >> 9, b = (blk - 2048) & 511;
        const float* s4[4] = {wq, wk, wv, wo};
        int frag = b * 4 + (threadIdx.x >> 6);     // 0..2047
        int nb = frag >> 5, kc = frag & 31;
        src = s4[w] + (size_t)(nb * 16 + lx) * Cn + kc * 32 + quad * 8;
        doff = NE + (size_t)w * WE + (size_t)frag * 512 + lane * 8;
    }
    f32x4 a = *(const f32x4*)(src);
    f32x4 b2 = *(const f32x4*)(src + 4);
    *(bf16x8*)(dst + doff) = pack8(a, b2);
}

// ---------------------------------------------------------------- QKV GEMM
// ZERO-LDS streaming GEMM (round-0 proven): 4 waves (2x2), wave 64x64,
// K-step 32, cur/next prefetch, no barriers. Epilogue: Q row-major;
// K frag-major; V natural-frag (8B short4v stores).
__global__ __launch_bounds__(256) void gemm_qkv_kernel(
    const bf16* __restrict__ Xf, const bf16* __restrict__ Wbase,
    bf16* __restrict__ Qo, bf16* __restrict__ Ko, bf16* __restrict__ Vo)
{
    const int bm = blockIdx.x, bn = blockIdx.y, wsel = blockIdx.z;
    const bf16* W = Wbase + (size_t)wsel * WE;
    const int tid  = threadIdx.x;
    const int wave = tid >> 6, lane = tid & 63;
    const int lx   = lane & 15, quad = lane >> 4;
    const int wm = wave >> 1, wn = wave & 1;

    const int mt0 = bm * 8 + wm * 4;
    const int nb0 = bn * 8 + wn * 4;
    const bf16* afrag = Xf + (size_t)mt0 * 32 * 512 + (size_t)lane * 8;
    const bf16* wfrag = W + (size_t)nb0 * 32 * 512 + (size_t)lane * 8;

    f32x4 acc[4][4] = {};   // [mt][nt]
    bf16x8 acur[4], bcur[4], anxt[4], bnxt[4];
#pragma unroll
    for (int i = 0; i < 4; ++i) {
        acur[i] = *(const bf16x8*)(afrag + (size_t)i * 32 * 512);
        bcur[i] = *(const bf16x8*)(wfrag + (size_t)i * 32 * 512);
    }
    for (int kc = 0; kc < 32; ++kc) {
        if (kc < 31) {
#pragma unroll
            for (int i = 0; i < 4; ++i) {
                anxt[i] = *(const bf16x8*)(afrag + ((size_t)i * 32 + kc + 1) * 512);
                bnxt[i] = *(const bf16x8*)(wfrag + ((size_t)i * 32 + kc + 1) * 512);
            }
        }
#pragma unroll
        for (int mt = 0; mt < 4; ++mt)
#pragma unroll
            for (int nt = 0; nt < 4; ++nt)
                acc[mt][nt] = MFMA16(acur[mt], bcur[nt], acc[mt][nt]);
#pragma unroll
        for (int i = 0; i < 4; ++i) { acur[i] = anxt[i]; bcur[i] = bnxt[i]; }
    }

    const int h = bn * 2 + wn;   // 64-col wave block == one head
    if (wsel <= 1) {             // fused RoPE: pair (d, d+32) = (nt, nt+2)
#pragma unroll
        for (int mt = 0; mt < 4; ++mt)
#pragma unroll
            for (int r = 0; r < 4; ++r) {
                int mg = bm * 128 + wm * 64 + mt * 16 + quad * 4 + r;
                int t  = mg & (Tn - 1);
#pragma unroll
                for (int nt = 0; nt < 2; ++nt) {
                    int d = nt * 16 + lx;   // 0..31
                    float ang = (float)t * __expf(-(float)d * 0.2878231366f);
                    float c, s;
                    __sincosf(ang, &s, &c);
                    float a0 = acc[mt][nt][r], a1 = acc[mt][nt + 2][r];
                    acc[mt][nt][r]     = a0 * c - a1 * s;
                    acc[mt][nt + 2][r] = a1 * c + a0 * s;
                }
            }
    }

#pragma unroll
    for (int mt = 0; mt < 4; ++mt) {
        int mg0 = bm * 128 + wm * 64 + mt * 16 + quad * 4;
        int b = mg0 >> 11, tlo = mg0 & (Tn - 1);
        if (wsel == 0) {        // Q: row-major [B,H,T,D], exp2-folded scale
#pragma unroll
            for (int nt = 0; nt < 4; ++nt)
#pragma unroll
                for (int r = 0; r < 4; ++r) {
                    int d = nt * 16 + lx;
                    Qo[((size_t)(b * Hn + h) * Tn + tlo + r) * Dn + d] =
                        __float2bfloat16(acc[mt][nt][r] * QSCALE);
                }
        } else if (wsel == 1) { // K: QK-B-fragment-major per head
            bf16* Kf = Ko + (size_t)(b * Hn + h) * Tn * Dn;
            int c = tlo >> 6, ntk = (tlo >> 4) & 3;
#pragma unroll
            for (int nt = 0; nt < 4; ++nt) {
                size_t base = ((size_t)(c * 4 + ntk) * 2 + (nt >> 1)) * 512
                            + (size_t)((nt & 1) * 2 + (lx >> 3)) * 128
                            + (size_t)(tlo & 15) * 8 + (lx & 7);
#pragma unroll
                for (int r = 0; r < 4; ++r)
                    Kf[base + (size_t)r * 8] = __float2bfloat16(acc[mt][nt][r]);
            }
        } else {                // V: natural-k frag-major, 8B stores (r13)
            bf16* Vf = Vo + (size_t)(b * Hn + h) * Tn * Dn;
            int c = tlo >> 6, ksv = (tlo >> 5) & 1;
            int qv = (tlo >> 3) & 3, pos0 = tlo & 7;
#pragma unroll
            for (int nt = 0; nt < 4; ++nt) {
                short4v pk;
#pragma unroll
                for (int r = 0; r < 4; ++r) pk[r] = (short)bfbits(acc[mt][nt][r]);
                *(short4v*)&Vf[((size_t)(c * 8 + nt * 2 + ksv)) * 512
                               + (size_t)qv * 128 + (size_t)lx * 8 + pos0] = pk;
            }
        }
    }
}

// ---------------------------------------------------------------- out GEMM
// ZERO-LDS streaming: block 128x64, wave 64x32, no barriers (round-0 form).
__global__ __launch_bounds__(256) void gemm_out_kernel(
    const bf16* __restrict__ Af, const bf16* __restrict__ W, float* __restrict__ Out)
{
    const int bm = blockIdx.x, bn = blockIdx.y;
    const int tid  = threadIdx.x;
    const int wave = tid >> 6, lane = tid & 63;
    const int lx   = lane & 15, quad = lane >> 4;
    const int wm = wave >> 1, wn = wave & 1;

    const int mt0 = bm * 8 + wm * 4;
    const int nb0 = bn * 4 + wn * 2;
    const bf16* afrag = Af + (size_t)mt0 * 32 * 512 + (size_t)lane * 8;
    const bf16* wfrag = W + (size_t)nb0 * 32 * 512 + (size_t)lane * 8;

    f32x4 acc[4][2] = {};
    bf16x8 acur[4], bcur[2], anxt[4], bnxt[2];
#pragma unroll
    for (int i = 0; i < 4; ++i)
        acur[i] = *(const bf16x8*)(afrag + (size_t)i * 32 * 512);
#pragma unroll
    for (int i = 0; i < 2; ++i)
        bcur[i] = *(const bf16x8*)(wfrag + (size_t)i * 32 * 512);
    for (int kc = 0; kc < 32; ++kc) {
        if (kc < 31) {
#pragma unroll
            for (int i = 0; i < 4; ++i)
                anxt[i] = *(const bf16x8*)(afrag + ((size_t)i * 32 + kc + 1) * 512);
#pragma unroll
            for (int i = 0; i < 2; ++i)
                bnxt[i] = *(const bf16x8*)(wfrag + ((size_t)i * 32 + kc + 1) * 512);
        }
#pragma unroll
        for (int mt = 0; mt < 4; ++mt)
#pragma unroll
            for (int nt = 0; nt < 2; ++nt)
                acc[mt][nt] = MFMA16(acur[mt], bcur[nt], acc[mt][nt]);
#pragma unroll
        for (int i = 0; i < 4; ++i) acur[i] = anxt[i];
#pragma unroll
        for (int i = 0; i < 2; ++i) bcur[i] = bnxt[i];
    }
#pragma unroll
    for (int mt = 0; mt < 4; ++mt)
#pragma unroll
        for (int nt = 0; nt < 2; ++nt)
#pragma unroll
            for (int r = 0; r < 4; ++r) {
                int mg = bm * 128 + wm * 64 + mt * 16 + quad * 4 + r;
                int ng = bn * 64 + wn * 32 + nt * 16 + lx;
                Out[(size_t)mg * Cn + ng] = acc[mt][nt][r];
            }
}

// ---------------------------------------------------------------- Attention
// 1024 blocks: f -> bh = (f&7)*4 + ((f>>3)&3), qb = 31 - (f>>5) (longest
// blocks dispatched first). One 64-row q-tile per block, 4 waves x 16 rows.
// ZERO-LDS K/V (global reads, L2-resident) + T15 double-pipeline:
//   iter c: read ap=P(c-1) | QK(c) | PV(c-1) | exp2->write P(c)
// so the LDS P round-trip is off the critical path and PV-MFMA overlaps
// the softmax VALU. Single per-wave P buffer (in-order DS, read-before-
// write program order on same addresses). P stride 68.
__global__ __launch_bounds__(256) void attn_kernel(
    const bf16* __restrict__ Q, const bf16* __restrict__ K,
    const bf16* __restrict__ Vt, bf16* __restrict__ O)
{
    __shared__ unsigned short Pl[4][16 * PS];
    const int f  = blockIdx.x;
    const int bh = (f & 7) * 4 + ((f >> 3) & 3);
    const int qb = 31 - (f >> 5);
    const int tid  = threadIdx.x;
    const int wave = tid >> 6, lane = tid & 63;
    const int lx   = lane & 15, quad = lane >> 4;

    const bf16* Qh = Q  + (size_t)bh * Tn * Dn;
    const bf16* Kh = K  + (size_t)bh * Tn * Dn;   // frag-major, 4096 shorts/chunk
    const bf16* Vh = Vt + (size_t)bh * Tn * Dn;   // natural-k frag-major
    unsigned short* pw = &Pl[wave][0];

    const int qrowA = qb * 64 + wave * 16 + lx;   // A-frag m index
    bf16x8 aq0 = *(const bf16x8*)(Qh + (size_t)qrowA * Dn + quad * 8);
    bf16x8 aq1 = *(const bf16x8*)(Qh + (size_t)qrowA * Dn + 32 + quad * 8);

    bf16x8 ones;
#pragma unroll
    for (int i = 0; i < 8; ++i) ones[i] = (short)0x3F80;

    f32x4 acc_o[4] = {};
    f32x4 acc_l = {};
    const int row_local = wave * 16 + quad * 4;

    bf16x8 kc[8], kn[8], vcur[8], vn[8];
    // ---- prologue: chunk 0 -> P(0)
#pragma unroll
    for (int i = 0; i < 8; ++i) {
        kc[i]   = *(const bf16x8*)(Kh + (size_t)i * 512 + lane * 8);
        vcur[i] = *(const bf16x8*)(Vh + (size_t)i * 512 + lane * 8);
    }
    {
        f32x4 accs[4] = {};
#pragma unroll
        for (int nt = 0; nt < 4; ++nt) {
            accs[nt] = MFMA16(aq0, kc[nt * 2], accs[nt]);
            accs[nt] = MFMA16(aq1, kc[nt * 2 + 1], accs[nt]);
        }
        if (qb > 0) {   // prefetch K(1)
#pragma unroll
            for (int i = 0; i < 8; ++i)
                kc[i] = *(const bf16x8*)(Kh + 4096 + (size_t)i * 512 + lane * 8);
#pragma unroll
            for (int nt = 0; nt < 4; ++nt)
#pragma unroll
                for (int r = 0; r < 4; ++r)
                    pw[(quad * 4 + r) * PS + nt * 16 + lx] = bfbits(exp2f(accs[nt][r]));
        } else {        // qb==0: chunk 0 is diagonal
#pragma unroll
            for (int nt = 0; nt < 4; ++nt) {
                int keyl = nt * 16 + lx;
#pragma unroll
                for (int r = 0; r < 4; ++r) {
                    float p = (keyl > row_local + r) ? 0.0f : exp2f(accs[nt][r]);
                    pw[(quad * 4 + r) * PS + nt * 16 + lx] = bfbits(p);
                }
            }
        }
    }

    // ---- main pipeline: iter c does QK/P(c) and PV(c-1)
    for (int c = 1; c <= qb; ++c) {
        // read P(c-1) first (latency overlaps QK below)
        bf16x8 ap0 = *(const bf16x8*)&pw[lx * PS + quad * 8];
        bf16x8 ap1 = *(const bf16x8*)&pw[lx * PS + 32 + quad * 8];
        // issue V(c) (consumed next iter) and K(c+1) (consumed next iter)
        const bf16* Vc = Vh + (size_t)c * 4096 + lane * 8;
#pragma unroll
        for (int i = 0; i < 8; ++i)
            vn[i] = *(const bf16x8*)(Vc + (size_t)i * 512);
        if (c < qb) {
            const bf16* Kc = Kh + (size_t)(c + 1) * 4096 + lane * 8;
#pragma unroll
            for (int i = 0; i < 8; ++i)
                kn[i] = *(const bf16x8*)(Kc + (size_t)i * 512);
        }
        // QK(c)
        f32x4 accs[4] = {};
#pragma unroll
        for (int nt = 0; nt < 4; ++nt) {
            accs[nt] = MFMA16(aq0, kc[nt * 2], accs[nt]);
            accs[nt] = MFMA16(aq1, kc[nt * 2 + 1], accs[nt]);
        }
        // PV(c-1): MFMA pipe, overlaps exp2/cvt below
        acc_l = MFMA16(ap0, ones, acc_l);
        acc_l = MFMA16(ap1, ones, acc_l);
#pragma unroll
        for (int dt = 0; dt < 4; ++dt) {
            acc_o[dt] = MFMA16(ap0, vcur[dt * 2], acc_o[dt]);
            acc_o[dt] = MFMA16(ap1, vcur[dt * 2 + 1], acc_o[dt]);
        }
        // P(c) -> LDS (after the ap reads in program order: same buffer safe)
        if (c < qb) {
#pragma unroll
            for (int nt = 0; nt < 4; ++nt)
#pragma unroll
                for (int r = 0; r < 4; ++r)
                    pw[(quad * 4 + r) * PS + nt * 16 + lx] = bfbits(exp2f(accs[nt][r]));
        } else {        // diagonal chunk
#pragma unroll
            for (int nt = 0; nt < 4; ++nt) {
                int keyl = nt * 16 + lx;
#pragma unroll
                for (int r = 0; r < 4; ++r) {
                    float p = (keyl > row_local + r) ? 0.0f : exp2f(accs[nt][r]);
                    pw[(quad * 4 + r) * PS + nt * 16 + lx] = bfbits(p);
                }
            }
        }
#pragma unroll
        for (int i = 0; i < 8; ++i) vcur[i] = vn[i];
        if (c < qb) {
#pragma unroll
            for (int i = 0; i < 8; ++i) kc[i] = kn[i];
        }
    }

    // ---- epilogue: PV(qb)
    {
        bf16x8 ap0 = *(const bf16x8*)&pw[lx * PS + quad * 8];
        bf16x8 ap1 = *(const bf16x8*)&pw[lx * PS + 32 + quad * 8];
        acc_l = MFMA16(ap0, ones, acc_l);
        acc_l = MFMA16(ap1, ones, acc_l);
#pragma unroll
        for (int dt = 0; dt < 4; ++dt) {
            acc_o[dt] = MFMA16(ap0, vcur[dt * 2], acc_o[dt]);
            acc_o[dt] = MFMA16(ap1, vcur[dt * 2 + 1], acc_o[dt]);
        }
    }

    // epilogue: fragment-major O write (for streaming out-GEMM)
    const int b = bh >> 4, h = bh & 15;
    const int mtile = b * 128 + qb * 4 + wave;
#pragma unroll
    for (int dt = 0; dt < 4; ++dt) {
        int ch = h * 64 + dt * 16 + lx;            // channel
        size_t base = ((size_t)mtile * 32 + (ch >> 5)) * 512
                    + (size_t)(((ch >> 3) & 3) * 16) * 8 + (ch & 7);
#pragma unroll
        for (int r = 0; r < 4; ++r) {
            float o = acc_o[dt][r] / acc_l[r];
            O[base + (size_t)(quad * 4 + r) * 8] = __float2bfloat16(o);
        }
    }
}

// ---------------------------------------------------------------- launch
extern "C" void kernel_launch(void* const* d_in, const int* in_sizes, int n_in,
                              void* d_out, int out_size, void* d_ws, size_t ws_size,
                              hipStream_t stream)
{
    const float* x  = (const float*)d_in[0];
    const float* Wq = (const float*)d_in[1];
    const float* Wk = (const float*)d_in[2];
    const float* Wv = (const float*)d_in[3];
    const float* Wo = (const float*)d_in[4];
    float* out = (float*)d_out;

    bf16* ws = (bf16*)d_ws;
    bf16* Xf = ws;                    // x fragment-major (aliased by Ab after QKV)
    bf16* Wb = ws + NE;               // Wq,Wk,Wv,Wo bf16 SHUFFLED, contiguous
    bf16* Qb = ws + NE + 4 * WE;      // [B,H,T,D] (pre-scaled by QSCALE)
    bf16* Kb = Qb + NE;               // QK-B-fragment-major per head
    bf16* Vb = Kb + NE;               // PV-B-fragment-major (natural k) per head
    bf16* Ab = Xf;                    // attention out FRAGMENT-MAJOR, reuses Xf

    convert_kernel<<<4096, 256, 0, stream>>>(x, Wq, Wk, Wv, Wo, ws);
    gemm_qkv_kernel<<<dim3(32, 8, 3), 256, 0, stream>>>(Xf, Wb, Qb, Kb, Vb);
    attn_kernel<<<1024, 256, 0, stream>>>(Qb, Kb, Vb, Ab);
    gemm_out_kernel<<<dim3(32, 16), 256, 0, stream>>>(Ab, Wb + 3 * WE, out);
}

// Round 5
// 178.784 us; speedup vs baseline: 1.0423x; 1.0423x over previous
//
#include <hip/hip_runtime.h>
#include <hip/hip_bf16.h>

// MultiHeadAttention fused pipeline. FP32 in/out, bf16 MFMA compute, fp32 accum.
// B=2 T=2048 C=1024 H=16 D=64.
// Stage 0: convert x,W* -> bf16 fragment-major (wave frag load = 1KB burst).
// Stage 1: QKV GEMM zero-LDS streaming (round-0 proven form); RoPE + exp2
//          scale fused. Q row-major; K QK-B-frag-major; V PV-B-frag-major
//          natural k-order (8B short4v stores).
// Stage 2: attention, ZERO-LDS-K/V + PING-PONG K PREFETCH: unroll-by-2 with
//          named register sets ka/kb (no copies -> compiler cannot sink the
//          prefetch; r3's 84-VGPR count proved copy-based prefetch was
//          defeated). V loaded at top of each step, consumed after softmax
//          (~400cy of QK+exp2+P-write covers L2 latency). P per-wave LDS
//          round-trip, stride 68 (0 conflicts).
// Stage 3: out GEMM zero-LDS streaming, 128x128 block / 64x64 wave (same
//          load:MFMA ratio as QKV: 8 loads per 16 MFMA).
//
// MFMA layouts (HW-verified): A[m=lane&15][k=quad*8+j]; B[n=lane&15][k=quad*8+j];
// C/D: row=quad*4+reg, col=lane&15.

typedef __hip_bfloat16 bf16;
typedef __attribute__((ext_vector_type(8))) short bf16x8;
typedef __attribute__((ext_vector_type(4))) float f32x4;
typedef __attribute__((ext_vector_type(4))) short short4v;

#define MFMA16(a, b, c) __builtin_amdgcn_mfma_f32_16x16x32_bf16((a), (b), (c), 0, 0, 0)

constexpr int Bn = 2, Hn = 16, Tn = 2048, Dn = 64, Cn = 1024;
constexpr size_t NE = (size_t)Bn * Tn * Cn;   // 4,194,304
constexpr size_t WE = (size_t)Cn * Cn;        // 1,048,576
constexpr float QSCALE = 0.125f * 1.44269504088896f;   // 1/8 * log2(e)
constexpr int PS = 68;   // P-buffer row stride in shorts (2-way banks = free)

__device__ inline unsigned short bfbits(float x) {
    bf16 b = __float2bfloat16(x);
    return *(unsigned short*)&b;
}

__device__ inline bf16x8 pack8(f32x4 a, f32x4 b) {
    bf16x8 r;
#pragma unroll
    for (int i = 0; i < 4; ++i) r[i] = (short)bfbits(a[i]);
#pragma unroll
    for (int i = 0; i < 4; ++i) r[4 + i] = (short)bfbits(b[i]);
    return r;
}

// ---------------------------------------------------------------- convert
// blocks [0,2048): x -> fragment-major. [2048,4096): W* -> fragment-major.
__global__ __launch_bounds__(256) void convert_kernel(
    const float* __restrict__ x, const float* __restrict__ wq,
    const float* __restrict__ wk, const float* __restrict__ wv,
    const float* __restrict__ wo, bf16* __restrict__ dst)
{
    int blk = blockIdx.x;
    int lane = threadIdx.x & 63;
    int lx = lane & 15, quad = lane >> 4;
    const float* src;
    size_t doff;
    if (blk < 2048) {
        int frag = blk * 4 + (threadIdx.x >> 6);   // 0..8191
        int mt = frag >> 5, kc = frag & 31;
        src = x + (size_t)(mt * 16 + lx) * Cn + kc * 32 + quad * 8;
        doff = (size_t)frag * 512 + lane * 8;
    } else {
        int w = (blk - 2048) >> 9, b = (blk - 2048) & 511;
        const float* s4[4] = {wq, wk, wv, wo};
        int frag = b * 4 + (threadIdx.x >> 6);     // 0..2047
        int nb = frag >> 5, kc = frag & 31;
        src = s4[w] + (size_t)(nb * 16 + lx) * Cn + kc * 32 + quad * 8;
        doff = NE + (size_t)w * WE + (size_t)frag * 512 + lane * 8;
    }
    f32x4 a = *(const f32x4*)(src);
    f32x4 b2 = *(const f32x4*)(src + 4);
    *(bf16x8*)(dst + doff) = pack8(a, b2);
}

// ---------------------------------------------------------------- QKV GEMM
// ZERO-LDS streaming GEMM (round-0 proven): 4 waves (2x2), wave 64x64,
// K-step 32, cur/next prefetch, no barriers. Epilogue: Q row-major;
// K frag-major; V natural-frag (8B short4v stores).
__global__ __launch_bounds__(256) void gemm_qkv_kernel(
    const bf16* __restrict__ Xf, const bf16* __restrict__ Wbase,
    bf16* __restrict__ Qo, bf16* __restrict__ Ko, bf16* __restrict__ Vo)
{
    const int bm = blockIdx.x, bn = blockIdx.y, wsel = blockIdx.z;
    const bf16* W = Wbase + (size_t)wsel * WE;
    const int tid  = threadIdx.x;
    const int wave = tid >> 6, lane = tid & 63;
    const int lx   = lane & 15, quad = lane >> 4;
    const int wm = wave >> 1, wn = wave & 1;

    const int mt0 = bm * 8 + wm * 4;
    const int nb0 = bn * 8 + wn * 4;
    const bf16* afrag = Xf + (size_t)mt0 * 32 * 512 + (size_t)lane * 8;
    const bf16* wfrag = W + (size_t)nb0 * 32 * 512 + (size_t)lane * 8;

    f32x4 acc[4][4] = {};   // [mt][nt]
    bf16x8 acur[4], bcur[4], anxt[4], bnxt[4];
#pragma unroll
    for (int i = 0; i < 4; ++i) {
        acur[i] = *(const bf16x8*)(afrag + (size_t)i * 32 * 512);
        bcur[i] = *(const bf16x8*)(wfrag + (size_t)i * 32 * 512);
    }
    for (int kc = 0; kc < 32; ++kc) {
        if (kc < 31) {
#pragma unroll
            for (int i = 0; i < 4; ++i) {
                anxt[i] = *(const bf16x8*)(afrag + ((size_t)i * 32 + kc + 1) * 512);
                bnxt[i] = *(const bf16x8*)(wfrag + ((size_t)i * 32 + kc + 1) * 512);
            }
        }
#pragma unroll
        for (int mt = 0; mt < 4; ++mt)
#pragma unroll
            for (int nt = 0; nt < 4; ++nt)
                acc[mt][nt] = MFMA16(acur[mt], bcur[nt], acc[mt][nt]);
#pragma unroll
        for (int i = 0; i < 4; ++i) { acur[i] = anxt[i]; bcur[i] = bnxt[i]; }
    }

    const int h = bn * 2 + wn;   // 64-col wave block == one head
    if (wsel <= 1) {             // fused RoPE: pair (d, d+32) = (nt, nt+2)
#pragma unroll
        for (int mt = 0; mt < 4; ++mt)
#pragma unroll
            for (int r = 0; r < 4; ++r) {
                int mg = bm * 128 + wm * 64 + mt * 16 + quad * 4 + r;
                int t  = mg & (Tn - 1);
#pragma unroll
                for (int nt = 0; nt < 2; ++nt) {
                    int d = nt * 16 + lx;   // 0..31
                    float ang = (float)t * __expf(-(float)d * 0.2878231366f);
                    float c, s;
                    __sincosf(ang, &s, &c);
                    float a0 = acc[mt][nt][r], a1 = acc[mt][nt + 2][r];
                    acc[mt][nt][r]     = a0 * c - a1 * s;
                    acc[mt][nt + 2][r] = a1 * c + a0 * s;
                }
            }
    }

#pragma unroll
    for (int mt = 0; mt < 4; ++mt) {
        int mg0 = bm * 128 + wm * 64 + mt * 16 + quad * 4;
        int b = mg0 >> 11, tlo = mg0 & (Tn - 1);
        if (wsel == 0) {        // Q: row-major [B,H,T,D], exp2-folded scale
#pragma unroll
            for (int nt = 0; nt < 4; ++nt)
#pragma unroll
                for (int r = 0; r < 4; ++r) {
                    int d = nt * 16 + lx;
                    Qo[((size_t)(b * Hn + h) * Tn + tlo + r) * Dn + d] =
                        __float2bfloat16(acc[mt][nt][r] * QSCALE);
                }
        } else if (wsel == 1) { // K: QK-B-fragment-major per head
            bf16* Kf = Ko + (size_t)(b * Hn + h) * Tn * Dn;
            int c = tlo >> 6, ntk = (tlo >> 4) & 3;
#pragma unroll
            for (int nt = 0; nt < 4; ++nt) {
                size_t base = ((size_t)(c * 4 + ntk) * 2 + (nt >> 1)) * 512
                            + (size_t)((nt & 1) * 2 + (lx >> 3)) * 128
                            + (size_t)(tlo & 15) * 8 + (lx & 7);
#pragma unroll
                for (int r = 0; r < 4; ++r)
                    Kf[base + (size_t)r * 8] = __float2bfloat16(acc[mt][nt][r]);
            }
        } else {                // V: natural-k frag-major, 8B stores (r13)
            bf16* Vf = Vo + (size_t)(b * Hn + h) * Tn * Dn;
            int c = tlo >> 6, ksv = (tlo >> 5) & 1;
            int qv = (tlo >> 3) & 3, pos0 = tlo & 7;
#pragma unroll
            for (int nt = 0; nt < 4; ++nt) {
                short4v pk;
#pragma unroll
                for (int r = 0; r < 4; ++r) pk[r] = (short)bfbits(acc[mt][nt][r]);
                *(short4v*)&Vf[((size_t)(c * 8 + nt * 2 + ksv)) * 512
                               + (size_t)qv * 128 + (size_t)lx * 8 + pos0] = pk;
            }
        }
    }
}

// ---------------------------------------------------------------- out GEMM
// ZERO-LDS streaming, 128x128 block / 64x64 wave (qkv-matched load:MFMA
// ratio 8:16). Grid (32, 8). fp32 row-major epilogue.
__global__ __launch_bounds__(256) void gemm_out_kernel(
    const bf16* __restrict__ Af, const bf16* __restrict__ W, float* __restrict__ Out)
{
    const int bm = blockIdx.x, bn = blockIdx.y;
    const int tid  = threadIdx.x;
    const int wave = tid >> 6, lane = tid & 63;
    const int lx   = lane & 15, quad = lane >> 4;
    const int wm = wave >> 1, wn = wave & 1;

    const int mt0 = bm * 8 + wm * 4;
    const int nb0 = bn * 8 + wn * 4;
    const bf16* afrag = Af + (size_t)mt0 * 32 * 512 + (size_t)lane * 8;
    const bf16* wfrag = W + (size_t)nb0 * 32 * 512 + (size_t)lane * 8;

    f32x4 acc[4][4] = {};
    bf16x8 acur[4], bcur[4], anxt[4], bnxt[4];
#pragma unroll
    for (int i = 0; i < 4; ++i) {
        acur[i] = *(const bf16x8*)(afrag + (size_t)i * 32 * 512);
        bcur[i] = *(const bf16x8*)(wfrag + (size_t)i * 32 * 512);
    }
    for (int kc = 0; kc < 32; ++kc) {
        if (kc < 31) {
#pragma unroll
            for (int i = 0; i < 4; ++i) {
                anxt[i] = *(const bf16x8*)(afrag + ((size_t)i * 32 + kc + 1) * 512);
                bnxt[i] = *(const bf16x8*)(wfrag + ((size_t)i * 32 + kc + 1) * 512);
            }
        }
#pragma unroll
        for (int mt = 0; mt < 4; ++mt)
#pragma unroll
            for (int nt = 0; nt < 4; ++nt)
                acc[mt][nt] = MFMA16(acur[mt], bcur[nt], acc[mt][nt]);
#pragma unroll
        for (int i = 0; i < 4; ++i) { acur[i] = anxt[i]; bcur[i] = bnxt[i]; }
    }
#pragma unroll
    for (int mt = 0; mt < 4; ++mt)
#pragma unroll
        for (int nt = 0; nt < 4; ++nt)
#pragma unroll
            for (int r = 0; r < 4; ++r) {
                int mg = bm * 128 + wm * 64 + mt * 16 + quad * 4 + r;
                int ng = bn * 128 + wn * 64 + nt * 16 + lx;
                Out[(size_t)mg * Cn + ng] = acc[mt][nt][r];
            }
}

// ---------------------------------------------------------------- Attention
// 1024 blocks: f -> bh = (f&7)*4 + ((f>>3)&3), qb = 31 - (f>>5) (longest
// blocks dispatched first). One 64-row q-tile per block, 4 waves x 16 rows.
// ZERO-LDS K/V (global reads, L2-resident). PING-PONG K prefetch: unroll-
// by-2 with named sets ka/kb, no register copies. V loaded at top of each
// step (QK+softmax covers its latency before PV). P per-wave LDS, stride 68.
__global__ __launch_bounds__(256) void attn_kernel(
    const bf16* __restrict__ Q, const bf16* __restrict__ K,
    const bf16* __restrict__ Vt, bf16* __restrict__ O)
{
    __shared__ unsigned short Pl[4][16 * PS];
    const int f  = blockIdx.x;
    const int bh = (f & 7) * 4 + ((f >> 3) & 3);
    const int qb = 31 - (f >> 5);
    const int tid  = threadIdx.x;
    const int wave = tid >> 6, lane = tid & 63;
    const int lx   = lane & 15, quad = lane >> 4;

    const bf16* Qh = Q  + (size_t)bh * Tn * Dn;
    const bf16* Kh = K  + (size_t)bh * Tn * Dn;   // frag-major, 4096 shorts/chunk
    const bf16* Vh = Vt + (size_t)bh * Tn * Dn;   // natural-k frag-major
    unsigned short* pw = &Pl[wave][0];

    const int qrowA = qb * 64 + wave * 16 + lx;   // A-frag m index
    bf16x8 aq0 = *(const bf16x8*)(Qh + (size_t)qrowA * Dn + quad * 8);
    bf16x8 aq1 = *(const bf16x8*)(Qh + (size_t)qrowA * Dn + 32 + quad * 8);

    bf16x8 ones;
#pragma unroll
    for (int i = 0; i < 8; ++i) ones[i] = (short)0x3F80;

    f32x4 acc_o[4] = {};
    f32x4 acc_l = {};
    const int row_local = wave * 16 + quad * 4;

    auto load8 = [&](bf16x8* d, const bf16* p) {
#pragma unroll
        for (int i = 0; i < 8; ++i) d[i] = *(const bf16x8*)(p + (size_t)i * 512);
    };

    // one attention step over a 64-key chunk: V load at top (latency hidden
    // under QK + softmax), QK MFMA, exp2->P LDS, P read, l and PV MFMA.
    auto step = [&](const bf16x8* k, const bf16* vptr, bool diag) {
        bf16x8 v[8];
#pragma unroll
        for (int i = 0; i < 8; ++i) v[i] = *(const bf16x8*)(vptr + (size_t)i * 512);
        f32x4 accs[4] = {};
#pragma unroll
        for (int nt = 0; nt < 4; ++nt) {
            accs[nt] = MFMA16(aq0, k[nt * 2], accs[nt]);
            accs[nt] = MFMA16(aq1, k[nt * 2 + 1], accs[nt]);
        }
        if (!diag) {
#pragma unroll
            for (int nt = 0; nt < 4; ++nt)
#pragma unroll
                for (int r = 0; r < 4; ++r)
                    pw[(quad * 4 + r) * PS + nt * 16 + lx] = bfbits(exp2f(accs[nt][r]));
        } else {   // diagonal chunk: causal mask
#pragma unroll
            for (int nt = 0; nt < 4; ++nt) {
                int keyl = nt * 16 + lx;
#pragma unroll
                for (int r = 0; r < 4; ++r) {
                    float p2 = (keyl > row_local + r) ? 0.0f : exp2f(accs[nt][r]);
                    pw[(quad * 4 + r) * PS + nt * 16 + lx] = bfbits(p2);
                }
            }
        }
        asm volatile("s_waitcnt lgkmcnt(0)" ::: "memory");
        bf16x8 ap0 = *(const bf16x8*)&pw[lx * PS + quad * 8];
        bf16x8 ap1 = *(const bf16x8*)&pw[lx * PS + 32 + quad * 8];
        acc_l = MFMA16(ap0, ones, acc_l);
        acc_l = MFMA16(ap1, ones, acc_l);
#pragma unroll
        for (int dt = 0; dt < 4; ++dt) {
            acc_o[dt] = MFMA16(ap0, v[dt * 2], acc_o[dt]);
            acc_o[dt] = MFMA16(ap1, v[dt * 2 + 1], acc_o[dt]);
        }
    };

    const bf16* kp = Kh + lane * 8;   // chunk base advances by 4096 shorts
    const bf16* vp = Vh + lane * 8;

    bf16x8 ka[8], kb[8];
    load8(ka, kp);                    // K(0)

    int ch = 0;
    while (ch + 1 <= qb) {            // unroll-by-2 ping-pong, no reg copies
        load8(kb, kp + 4096);                     // K(ch+1) into other set
        step(ka, vp, false);                      // chunk ch  (ch < qb)
        if (ch + 2 <= qb) load8(ka, kp + 8192);   // K(ch+2) into first set
        step(kb, vp + 4096, (ch + 1) == qb);      // chunk ch+1
        kp += 8192; vp += 8192; ch += 2;
    }
    if (ch == qb)                     // even-count tail: diagonal chunk
        step(ka, vp, true);

    // epilogue: fragment-major O write (for streaming out-GEMM)
    const int b = bh >> 4, h = bh & 15;
    const int mtile = b * 128 + qb * 4 + wave;
#pragma unroll
    for (int dt = 0; dt < 4; ++dt) {
        int ch2 = h * 64 + dt * 16 + lx;           // channel
        size_t base = ((size_t)mtile * 32 + (ch2 >> 5)) * 512
                    + (size_t)(((ch2 >> 3) & 3) * 16) * 8 + (ch2 & 7);
#pragma unroll
        for (int r = 0; r < 4; ++r) {
            float o = acc_o[dt][r] / acc_l[r];
            O[base + (size_t)(quad * 4 + r) * 8] = __float2bfloat16(o);
        }
    }
}

// ---------------------------------------------------------------- launch
extern "C" void kernel_launch(void* const* d_in, const int* in_sizes, int n_in,
                              void* d_out, int out_size, void* d_ws, size_t ws_size,
                              hipStream_t stream)
{
    const float* x  = (const float*)d_in[0];
    const float* Wq = (const float*)d_in[1];
    const float* Wk = (const float*)d_in[2];
    const float* Wv = (const float*)d_in[3];
    const float* Wo = (const float*)d_in[4];
    float* out = (float*)d_out;

    bf16* ws = (bf16*)d_ws;
    bf16* Xf = ws;                    // x fragment-major (aliased by Ab after QKV)
    bf16* Wb = ws + NE;               // Wq,Wk,Wv,Wo bf16 SHUFFLED, contiguous
    bf16* Qb = ws + NE + 4 * WE;      // [B,H,T,D] (pre-scaled by QSCALE)
    bf16* Kb = Qb + NE;               // QK-B-fragment-major per head
    bf16* Vb = Kb + NE;               // PV-B-fragment-major (natural k) per head
    bf16* Ab = Xf;                    // attention out FRAGMENT-MAJOR, reuses Xf

    convert_kernel<<<4096, 256, 0, stream>>>(x, Wq, Wk, Wv, Wo, ws);
    gemm_qkv_kernel<<<dim3(32, 8, 3), 256, 0, stream>>>(Xf, Wb, Qb, Kb, Vb);
    attn_kernel<<<1024, 256, 0, stream>>>(Qb, Kb, Vb, Ab);
    gemm_out_kernel<<<dim3(32, 8), 256, 0, stream>>>(Ab, Wb + 3 * WE, out);
}

// Round 6
// 177.961 us; speedup vs baseline: 1.0471x; 1.0046x over previous
//
#include <hip/hip_runtime.h>
#include <hip/hip_bf16.h>

// MultiHeadAttention fused pipeline. FP32 in/out, bf16 MFMA compute, fp32 accum.
// B=2 T=2048 C=1024 H=16 D=64.
// Stage 0: convert x,W* -> bf16 fragment-major (wave frag load = 1KB burst).
// Stage 1: QKV GEMM zero-LDS streaming; RoPE + exp2 scale fused. Q row-major;
//          K QK-B-frag-major; V PV-B-frag-major natural k (8B short4v stores).
// Stage 2: attention with CAUSAL-PAIRED Q-TILES: block g handles q-tiles
//          tHi=31-p and tLo=p of head bh (g&31). Both tiles scan K/V chunks
//          from 0, so one K/V register load per chunk feeds TWO tile-steps
//          while c<=p. Every block does exactly 33 tile-steps (perfect
//          balance); 512 blocks x 4 waves at <=256 VGPR = 2 blocks/CU ->
//          whole grid resident, no occupancy-decay tail. bh=g&31 keeps
//          same-bh blocks on one XCD (g%8==bh%8) for K/V L2 locality.
//          Zero-LDS K/V (L2-resident, frag-major = register order);
//          P per-wave LDS round-trip, stride 68 (0 conflicts).
// Stage 3: out GEMM zero-LDS streaming 128x128 block / 64x64 wave.
//
// MFMA layouts (HW-verified): A[m=lane&15][k=quad*8+j]; B[n=lane&15][k=quad*8+j];
// C/D: row=quad*4+reg, col=lane&15.

typedef __hip_bfloat16 bf16;
typedef __attribute__((ext_vector_type(8))) short bf16x8;
typedef __attribute__((ext_vector_type(4))) float f32x4;
typedef __attribute__((ext_vector_type(4))) short short4v;

#define MFMA16(a, b, c) __builtin_amdgcn_mfma_f32_16x16x32_bf16((a), (b), (c), 0, 0, 0)

constexpr int Bn = 2, Hn = 16, Tn = 2048, Dn = 64, Cn = 1024;
constexpr size_t NE = (size_t)Bn * Tn * Cn;   // 4,194,304
constexpr size_t WE = (size_t)Cn * Cn;        // 1,048,576
constexpr float QSCALE = 0.125f * 1.44269504088896f;   // 1/8 * log2(e)
constexpr int PS = 68;   // P-buffer row stride in shorts (2-way banks = free)

__device__ inline unsigned short bfbits(float x) {
    bf16 b = __float2bfloat16(x);
    return *(unsigned short*)&b;
}

__device__ inline bf16x8 pack8(f32x4 a, f32x4 b) {
    bf16x8 r;
#pragma unroll
    for (int i = 0; i < 4; ++i) r[i] = (short)bfbits(a[i]);
#pragma unroll
    for (int i = 0; i < 4; ++i) r[4 + i] = (short)bfbits(b[i]);
    return r;
}

// ---------------------------------------------------------------- convert
// blocks [0,2048): x -> fragment-major. [2048,4096): W* -> fragment-major.
__global__ __launch_bounds__(256) void convert_kernel(
    const float* __restrict__ x, const float* __restrict__ wq,
    const float* __restrict__ wk, const float* __restrict__ wv,
    const float* __restrict__ wo, bf16* __restrict__ dst)
{
    int blk = blockIdx.x;
    int lane = threadIdx.x & 63;
    int lx = lane & 15, quad = lane >> 4;
    const float* src;
    size_t doff;
    if (blk < 2048) {
        int frag = blk * 4 + (threadIdx.x >> 6);   // 0..8191
        int mt = frag >> 5, kc = frag & 31;
        src = x + (size_t)(mt * 16 + lx) * Cn + kc * 32 + quad * 8;
        doff = (size_t)frag * 512 + lane * 8;
    } else {
        int w = (blk - 2048) >> 9, b = (blk - 2048) & 511;
        const float* s4[4] = {wq, wk, wv, wo};
        int frag = b * 4 + (threadIdx.x >> 6);     // 0..2047
        int nb = frag >> 5, kc = frag & 31;
        src = s4[w] + (size_t)(nb * 16 + lx) * Cn + kc * 32 + quad * 8;
        doff = NE + (size_t)w * WE + (size_t)frag * 512 + lane * 8;
    }
    f32x4 a = *(const f32x4*)(src);
    f32x4 b2 = *(const f32x4*)(src + 4);
    *(bf16x8*)(dst + doff) = pack8(a, b2);
}

// ---------------------------------------------------------------- QKV GEMM
// ZERO-LDS streaming GEMM (round-0 proven): 4 waves (2x2), wave 64x64,
// K-step 32, cur/next prefetch, no barriers. Epilogue: Q row-major;
// K frag-major; V natural-frag (8B short4v stores).
__global__ __launch_bounds__(256) void gemm_qkv_kernel(
    const bf16* __restrict__ Xf, const bf16* __restrict__ Wbase,
    bf16* __restrict__ Qo, bf16* __restrict__ Ko, bf16* __restrict__ Vo)
{
    const int bm = blockIdx.x, bn = blockIdx.y, wsel = blockIdx.z;
    const bf16* W = Wbase + (size_t)wsel * WE;
    const int tid  = threadIdx.x;
    const int wave = tid >> 6, lane = tid & 63;
    const int lx   = lane & 15, quad = lane >> 4;
    const int wm = wave >> 1, wn = wave & 1;

    const int mt0 = bm * 8 + wm * 4;
    const int nb0 = bn * 8 + wn * 4;
    const bf16* afrag = Xf + (size_t)mt0 * 32 * 512 + (size_t)lane * 8;
    const bf16* wfrag = W + (size_t)nb0 * 32 * 512 + (size_t)lane * 8;

    f32x4 acc[4][4] = {};   // [mt][nt]
    bf16x8 acur[4], bcur[4], anxt[4], bnxt[4];
#pragma unroll
    for (int i = 0; i < 4; ++i) {
        acur[i] = *(const bf16x8*)(afrag + (size_t)i * 32 * 512);
        bcur[i] = *(const bf16x8*)(wfrag + (size_t)i * 32 * 512);
    }
    for (int kc = 0; kc < 32; ++kc) {
        if (kc < 31) {
#pragma unroll
            for (int i = 0; i < 4; ++i) {
                anxt[i] = *(const bf16x8*)(afrag + ((size_t)i * 32 + kc + 1) * 512);
                bnxt[i] = *(const bf16x8*)(wfrag + ((size_t)i * 32 + kc + 1) * 512);
            }
        }
#pragma unroll
        for (int mt = 0; mt < 4; ++mt)
#pragma unroll
            for (int nt = 0; nt < 4; ++nt)
                acc[mt][nt] = MFMA16(acur[mt], bcur[nt], acc[mt][nt]);
#pragma unroll
        for (int i = 0; i < 4; ++i) { acur[i] = anxt[i]; bcur[i] = bnxt[i]; }
    }

    const int h = bn * 2 + wn;   // 64-col wave block == one head
    if (wsel <= 1) {             // fused RoPE: pair (d, d+32) = (nt, nt+2)
#pragma unroll
        for (int mt = 0; mt < 4; ++mt)
#pragma unroll
            for (int r = 0; r < 4; ++r) {
                int mg = bm * 128 + wm * 64 + mt * 16 + quad * 4 + r;
                int t  = mg & (Tn - 1);
#pragma unroll
                for (int nt = 0; nt < 2; ++nt) {
                    int d = nt * 16 + lx;   // 0..31
                    float ang = (float)t * __expf(-(float)d * 0.2878231366f);
                    float c, s;
                    __sincosf(ang, &s, &c);
                    float a0 = acc[mt][nt][r], a1 = acc[mt][nt + 2][r];
                    acc[mt][nt][r]     = a0 * c - a1 * s;
                    acc[mt][nt + 2][r] = a1 * c + a0 * s;
                }
            }
    }

#pragma unroll
    for (int mt = 0; mt < 4; ++mt) {
        int mg0 = bm * 128 + wm * 64 + mt * 16 + quad * 4;
        int b = mg0 >> 11, tlo = mg0 & (Tn - 1);
        if (wsel == 0) {        // Q: row-major [B,H,T,D], exp2-folded scale
#pragma unroll
            for (int nt = 0; nt < 4; ++nt)
#pragma unroll
                for (int r = 0; r < 4; ++r) {
                    int d = nt * 16 + lx;
                    Qo[((size_t)(b * Hn + h) * Tn + tlo + r) * Dn + d] =
                        __float2bfloat16(acc[mt][nt][r] * QSCALE);
                }
        } else if (wsel == 1) { // K: QK-B-fragment-major per head
            bf16* Kf = Ko + (size_t)(b * Hn + h) * Tn * Dn;
            int c = tlo >> 6, ntk = (tlo >> 4) & 3;
#pragma unroll
            for (int nt = 0; nt < 4; ++nt) {
                size_t base = ((size_t)(c * 4 + ntk) * 2 + (nt >> 1)) * 512
                            + (size_t)((nt & 1) * 2 + (lx >> 3)) * 128
                            + (size_t)(tlo & 15) * 8 + (lx & 7);
#pragma unroll
                for (int r = 0; r < 4; ++r)
                    Kf[base + (size_t)r * 8] = __float2bfloat16(acc[mt][nt][r]);
            }
        } else {                // V: natural-k frag-major, 8B stores (r13)
            bf16* Vf = Vo + (size_t)(b * Hn + h) * Tn * Dn;
            int c = tlo >> 6, ksv = (tlo >> 5) & 1;
            int qv = (tlo >> 3) & 3, pos0 = tlo & 7;
#pragma unroll
            for (int nt = 0; nt < 4; ++nt) {
                short4v pk;
#pragma unroll
                for (int r = 0; r < 4; ++r) pk[r] = (short)bfbits(acc[mt][nt][r]);
                *(short4v*)&Vf[((size_t)(c * 8 + nt * 2 + ksv)) * 512
                               + (size_t)qv * 128 + (size_t)lx * 8 + pos0] = pk;
            }
        }
    }
}

// ---------------------------------------------------------------- out GEMM
// ZERO-LDS streaming, 128x128 block / 64x64 wave. Grid (32, 8).
__global__ __launch_bounds__(256) void gemm_out_kernel(
    const bf16* __restrict__ Af, const bf16* __restrict__ W, float* __restrict__ Out)
{
    const int bm = blockIdx.x, bn = blockIdx.y;
    const int tid  = threadIdx.x;
    const int wave = tid >> 6, lane = tid & 63;
    const int lx   = lane & 15, quad = lane >> 4;
    const int wm = wave >> 1, wn = wave & 1;

    const int mt0 = bm * 8 + wm * 4;
    const int nb0 = bn * 8 + wn * 4;
    const bf16* afrag = Af + (size_t)mt0 * 32 * 512 + (size_t)lane * 8;
    const bf16* wfrag = W + (size_t)nb0 * 32 * 512 + (size_t)lane * 8;

    f32x4 acc[4][4] = {};
    bf16x8 acur[4], bcur[4], anxt[4], bnxt[4];
#pragma unroll
    for (int i = 0; i < 4; ++i) {
        acur[i] = *(const bf16x8*)(afrag + (size_t)i * 32 * 512);
        bcur[i] = *(const bf16x8*)(wfrag + (size_t)i * 32 * 512);
    }
    for (int kc = 0; kc < 32; ++kc) {
        if (kc < 31) {
#pragma unroll
            for (int i = 0; i < 4; ++i) {
                anxt[i] = *(const bf16x8*)(afrag + ((size_t)i * 32 + kc + 1) * 512);
                bnxt[i] = *(const bf16x8*)(wfrag + ((size_t)i * 32 + kc + 1) * 512);
            }
        }
#pragma unroll
        for (int mt = 0; mt < 4; ++mt)
#pragma unroll
            for (int nt = 0; nt < 4; ++nt)
                acc[mt][nt] = MFMA16(acur[mt], bcur[nt], acc[mt][nt]);
#pragma unroll
        for (int i = 0; i < 4; ++i) { acur[i] = anxt[i]; bcur[i] = bnxt[i]; }
    }
#pragma unroll
    for (int mt = 0; mt < 4; ++mt)
#pragma unroll
        for (int nt = 0; nt < 4; ++nt)
#pragma unroll
            for (int r = 0; r < 4; ++r) {
                int mg = bm * 128 + wm * 64 + mt * 16 + quad * 4 + r;
                int ng = bn * 128 + wn * 64 + nt * 16 + lx;
                Out[(size_t)mg * Cn + ng] = acc[mt][nt][r];
            }
}

// ---------------------------------------------------------------- Attention
// 512 blocks: g -> bh = g&31 (g%8==bh%8: same-bh blocks share an XCD L2),
// pair p = g>>5 in [0,16). Block handles q-tiles tHi=31-p and tLo=p.
// Per chunk c (0..tHi): one shared K/V register load; hi tile-step always,
// lo tile-step while c<=tLo. Exactly 33 tile-steps per block (balanced).
// Zero-LDS K/V; P per-wave LDS round-trip, stride 68.
__global__ __launch_bounds__(256, 2) void attn_kernel(
    const bf16* __restrict__ Q, const bf16* __restrict__ K,
    const bf16* __restrict__ Vt, bf16* __restrict__ O)
{
    __shared__ unsigned short Pl[4][16 * PS];
    const int g  = blockIdx.x;
    const int bh = g & 31;
    const int p  = g >> 5;              // 0..15
    const int tHi = 31 - p, tLo = p;    // tHi >= 16 > 15 >= tLo
    const int tid  = threadIdx.x;
    const int wave = tid >> 6, lane = tid & 63;
    const int lx   = lane & 15, quad = lane >> 4;

    const bf16* Qh = Q  + (size_t)bh * Tn * Dn;
    const bf16* Kh = K  + (size_t)bh * Tn * Dn;   // frag-major, 4096 shorts/chunk
    const bf16* Vh = Vt + (size_t)bh * Tn * Dn;   // natural-k frag-major
    unsigned short* pw = &Pl[wave][0];

    const int qrowH = tHi * 64 + wave * 16 + lx;  // A-frag m index (hi tile)
    bf16x8 aqH0 = *(const bf16x8*)(Qh + (size_t)qrowH * Dn + quad * 8);
    bf16x8 aqH1 = *(const bf16x8*)(Qh + (size_t)qrowH * Dn + 32 + quad * 8);
    const int qrowL = tLo * 64 + wave * 16 + lx;  // (lo tile)
    bf16x8 aqL0 = *(const bf16x8*)(Qh + (size_t)qrowL * Dn + quad * 8);
    bf16x8 aqL1 = *(const bf16x8*)(Qh + (size_t)qrowL * Dn + 32 + quad * 8);

    bf16x8 ones;
#pragma unroll
    for (int i = 0; i < 8; ++i) ones[i] = (short)0x3F80;

    f32x4 acc_oH[4] = {}, acc_oL[4] = {};
    f32x4 acc_lH = {},    acc_lL = {};
    const int row_local = wave * 16 + quad * 4;

    // softmax -> per-wave P buffer (slot = key, natural order)
    auto storeP = [&](const f32x4* accs, bool diag) {
        if (!diag) {
#pragma unroll
            for (int nt = 0; nt < 4; ++nt)
#pragma unroll
                for (int r = 0; r < 4; ++r)
                    pw[(quad * 4 + r) * PS + nt * 16 + lx] = bfbits(exp2f(accs[nt][r]));
        } else {
#pragma unroll
            for (int nt = 0; nt < 4; ++nt) {
                int keyl = nt * 16 + lx;
#pragma unroll
                for (int r = 0; r < 4; ++r) {
                    float pv = (keyl > row_local + r) ? 0.0f : exp2f(accs[nt][r]);
                    pw[(quad * 4 + r) * PS + nt * 16 + lx] = bfbits(pv);
                }
            }
        }
    };

    for (int c = 0; c <= tHi; ++c) {
        // shared K/V chunk load (registers; L2-resident frag-major layout)
        const bf16* kp = Kh + (size_t)c * 4096 + lane * 8;
        const bf16* vp = Vh + (size_t)c * 4096 + lane * 8;
        bf16x8 k[8], v[8];
#pragma unroll
        for (int i = 0; i < 8; ++i) {
            k[i] = *(const bf16x8*)(kp + (size_t)i * 512);
            v[i] = *(const bf16x8*)(vp + (size_t)i * 512);
        }
        const bool lo = (c <= tLo);
        // QK for both tiles first (independent MFMAs; scheduler freedom)
        f32x4 accsH[4] = {};
#pragma unroll
        for (int nt = 0; nt < 4; ++nt) {
            accsH[nt] = MFMA16(aqH0, k[nt * 2], accsH[nt]);
            accsH[nt] = MFMA16(aqH1, k[nt * 2 + 1], accsH[nt]);
        }
        f32x4 accsL[4] = {};
        if (lo) {
#pragma unroll
            for (int nt = 0; nt < 4; ++nt) {
                accsL[nt] = MFMA16(aqL0, k[nt * 2], accsL[nt]);
                accsL[nt] = MFMA16(aqL1, k[nt * 2 + 1], accsL[nt]);
            }
        }
        // ---- hi tile: softmax -> P -> l,PV
        storeP(accsH, c == tHi);
        asm volatile("s_waitcnt lgkmcnt(0)" ::: "memory");
        {
            bf16x8 ap0 = *(const bf16x8*)&pw[lx * PS + quad * 8];
            bf16x8 ap1 = *(const bf16x8*)&pw[lx * PS + 32 + quad * 8];
            acc_lH = MFMA16(ap0, ones, acc_lH);
            acc_lH = MFMA16(ap1, ones, acc_lH);
#pragma unroll
            for (int dt = 0; dt < 4; ++dt) {
                acc_oH[dt] = MFMA16(ap0, v[dt * 2], acc_oH[dt]);
                acc_oH[dt] = MFMA16(ap1, v[dt * 2 + 1], acc_oH[dt]);
            }
        }
        // ---- lo tile: same P buffer reused (same-wave DS ops are in-order)
        if (lo) {
            storeP(accsL, c == tLo);
            asm volatile("s_waitcnt lgkmcnt(0)" ::: "memory");
            bf16x8 ap0 = *(const bf16x8*)&pw[lx * PS + quad * 8];
            bf16x8 ap1 = *(const bf16x8*)&pw[lx * PS + 32 + quad * 8];
            acc_lL = MFMA16(ap0, ones, acc_lL);
            acc_lL = MFMA16(ap1, ones, acc_lL);
#pragma unroll
            for (int dt = 0; dt < 4; ++dt) {
                acc_oL[dt] = MFMA16(ap0, v[dt * 2], acc_oL[dt]);
                acc_oL[dt] = MFMA16(ap1, v[dt * 2 + 1], acc_oL[dt]);
            }
        }
    }

    // epilogues: fragment-major O writes (for streaming out-GEMM)
    const int b = bh >> 4, h = bh & 15;
    auto writeO = [&](int t, const f32x4* acc_o, const f32x4& acc_l) {
        const int mtile = b * 128 + t * 4 + wave;
#pragma unroll
        for (int dt = 0; dt < 4; ++dt) {
            int ch = h * 64 + dt * 16 + lx;        // channel
            size_t base = ((size_t)mtile * 32 + (ch >> 5)) * 512
                        + (size_t)(((ch >> 3) & 3) * 16) * 8 + (ch & 7);
#pragma unroll
            for (int r = 0; r < 4; ++r) {
                float o = acc_o[dt][r] / acc_l[r];
                O[base + (size_t)(quad * 4 + r) * 8] = __float2bfloat16(o);
            }
        }
    };
    writeO(tHi, acc_oH, acc_lH);
    writeO(tLo, acc_oL, acc_lL);
}

// ---------------------------------------------------------------- launch
extern "C" void kernel_launch(void* const* d_in, const int* in_sizes, int n_in,
                              void* d_out, int out_size, void* d_ws, size_t ws_size,
                              hipStream_t stream)
{
    const float* x  = (const float*)d_in[0];
    const float* Wq = (const float*)d_in[1];
    const float* Wk = (const float*)d_in[2];
    const float* Wv = (const float*)d_in[3];
    const float* Wo = (const float*)d_in[4];
    float* out = (float*)d_out;

    bf16* ws = (bf16*)d_ws;
    bf16* Xf = ws;                    // x fragment-major (aliased by Ab after QKV)
    bf16* Wb = ws + NE;               // Wq,Wk,Wv,Wo bf16 SHUFFLED, contiguous
    bf16* Qb = ws + NE + 4 * WE;      // [B,H,T,D] (pre-scaled by QSCALE)
    bf16* Kb = Qb + NE;               // QK-B-fragment-major per head
    bf16* Vb = Kb + NE;               // PV-B-fragment-major (natural k) per head
    bf16* Ab = Xf;                    // attention out FRAGMENT-MAJOR, reuses Xf

    convert_kernel<<<4096, 256, 0, stream>>>(x, Wq, Wk, Wv, Wo, ws);
    gemm_qkv_kernel<<<dim3(32, 8, 3), 256, 0, stream>>>(Xf, Wb, Qb, Kb, Vb);
    attn_kernel<<<512, 256, 0, stream>>>(Qb, Kb, Vb, Ab);
    gemm_out_kernel<<<dim3(32, 8), 256, 0, stream>>>(Ab, Wb + 3 * WE, out);
}